// Round 2
// baseline (2439.985 us; speedup 1.0000x reference)
//
#include <hip/hip_runtime.h>
#include <hip/hip_bf16.h>

typedef _Float16 f16;
typedef __attribute__((ext_vector_type(8))) _Float16 f16x8;
typedef __attribute__((ext_vector_type(2))) _Float16 f16x2;
typedef __attribute__((ext_vector_type(4))) float f32x4;

constexpr int CB = 64, CP = 196, CH = 512, CV = 30000, CVP = 30080, CT = 20;

__device__ __forceinline__ float sigf(float x) { return 1.f / (1.f + __expf(-x)); }

// permutation: orig gate row r (q = r>>9 gate type, m = r&511 h-dim) ->
// r' = 32*(m>>3) + 8*q + (m&7); block k of 64 owns cols [32k,32k+32) = h-dims [8k,8k+8)
__device__ __forceinline__ int pm(int r) {
    return (((r & 511) >> 3) << 5) + ((r >> 9) << 3) + (r & 7);
}

#if defined(__has_builtin)
#if __has_builtin(__builtin_amdgcn_fdot2)
#define HAVE_FDOT2 1
#endif
#endif

__device__ __forceinline__ float dot8(f16x8 a, f16x8 b, float c) {
#ifdef HAVE_FDOT2
#pragma unroll
    for (int i = 0; i < 4; ++i) {
        f16x2 av, bv;
        av[0] = a[2 * i]; av[1] = a[2 * i + 1];
        bv[0] = b[2 * i]; bv[1] = b[2 * i + 1];
        c = __builtin_amdgcn_fdot2(av, bv, c, false);
    }
#else
#pragma unroll
    for (int i = 0; i < 8; ++i) c = fmaf((float)a[i], (float)b[i], c);
#endif
    return c;
}

// device-scope barrier; requires all blocks resident (grid=64 << 256 CUs)
__device__ __forceinline__ void gbar(int* cnt, int expected) {
    __threadfence();
    __syncthreads();
    if (threadIdx.x == 0) {
        __hip_atomic_fetch_add(cnt, 1, __ATOMIC_ACQ_REL, __HIP_MEMORY_SCOPE_AGENT);
        while (__hip_atomic_load(cnt, __ATOMIC_ACQUIRE, __HIP_MEMORY_SCOPE_AGENT) < expected) {
            __builtin_amdgcn_s_sleep(2);
        }
    }
    __syncthreads();
    __threadfence();
}

// ---------------------------------------------------------------------------
// mega convert/gather/prep kernel (one dispatch for the whole prologue prep)
// ---------------------------------------------------------------------------
__device__ __forceinline__ void cvt8(const float* __restrict__ s, f16* __restrict__ d) {
    float4 a = *(const float4*)s;
    float4 b = *(const float4*)(s + 4);
    f16x8 o;
    o[0] = (f16)a.x; o[1] = (f16)a.y; o[2] = (f16)a.z; o[3] = (f16)a.w;
    o[4] = (f16)b.x; o[5] = (f16)b.y; o[6] = (f16)b.z; o[7] = (f16)b.w;
    *(f16x8*)d = o;
}

__global__ __launch_bounds__(256) void k_mega(
    const float* __restrict__ enc, const float* __restrict__ W_ea,
    const float* __restrict__ W_da, const float* __restrict__ W_fb,
    const float* __restrict__ W_ih, const float* __restrict__ W_hh,
    const float* __restrict__ W_fc, const float* __restrict__ emb,
    const int* __restrict__ caps, const float* __restrict__ b_da,
    const float* __restrict__ b_fb, const float* __restrict__ b_ih,
    const float* __restrict__ b_hh,
    f16* __restrict__ enc_h, f16* __restrict__ Wea_h, f16* __restrict__ Wdafb_h,
    f16* __restrict__ WihE_p, f16* __restrict__ Bg, f16* __restrict__ Wfc_h,
    f16* __restrict__ embg, float* __restrict__ bcat, float* __restrict__ bsum_p,
    int* __restrict__ gsync)
{
    constexpr long long E0 = 802816;    // enc cvt (12544*512/8)
    constexpr long long E1 = 835584;    // W_ea
    constexpr long long E2 = 868352;    // W_da -> Wdafb[0:512]
    constexpr long long E3 = 901120;    // W_fb -> Wdafb[512:1024]
    constexpr long long E4 = 1032192;   // W_ih cols 0..511 perm -> WihE_p
    constexpr long long E5 = 1163264;   // W_ih cols 512..1023 perm -> Bg[:, :512]
    constexpr long long E6 = 1294336;   // W_hh perm -> Bg[:, 512:]
    constexpr long long E7 = 3214336;   // W_fc
    constexpr long long E8 = 3296256;   // emb gather
    constexpr long long E9 = 3301376;   // Wfc pad zeros
    constexpr long long E10 = 3304448;  // biases
    constexpr long long TOT = 3304449;  // + gsync zero

    for (long long id = (long long)blockIdx.x * 256 + threadIdx.x; id < TOT;
         id += (long long)gridDim.x * 256) {
        if (id < E0) {
            cvt8(enc + id * 8, enc_h + id * 8);
        } else if (id < E1) {
            long long c = id - E0; cvt8(W_ea + c * 8, Wea_h + c * 8);
        } else if (id < E2) {
            long long c = id - E1; cvt8(W_da + c * 8, Wdafb_h + c * 8);
        } else if (id < E3) {
            long long c = id - E2; cvt8(W_fb + c * 8, Wdafb_h + 262144 + c * 8);
        } else if (id < E4) {
            long long c = id - E3; int r = (int)(c >> 6), j = (int)(c & 63);
            cvt8(W_ih + (size_t)r * 1024 + j * 8, WihE_p + (size_t)pm(r) * 512 + j * 8);
        } else if (id < E5) {
            long long c = id - E4; int r = (int)(c >> 6), j = (int)(c & 63);
            cvt8(W_ih + (size_t)r * 1024 + 512 + j * 8, Bg + (size_t)pm(r) * 1024 + j * 8);
        } else if (id < E6) {
            long long c = id - E5; int r = (int)(c >> 6), j = (int)(c & 63);
            cvt8(W_hh + (size_t)r * 512 + j * 8, Bg + (size_t)pm(r) * 1024 + 512 + j * 8);
        } else if (id < E7) {
            long long c = id - E6; cvt8(W_fc + c * 8, Wfc_h + c * 8);
        } else if (id < E8) {
            long long c = id - E7; int m = (int)(c >> 6), j = (int)(c & 63);
            int tt = m >> 6, bb = m & 63;
            int row = caps[bb * 21 + tt];
            cvt8(emb + (size_t)row * 512 + j * 8, embg + (size_t)m * 512 + j * 8);
        } else if (id < E9) {
            long long c = id - E8; f16x8 z = {};
            *(f16x8*)&Wfc_h[15360000 + c * 8] = z;
        } else if (id < E10) {
            int i = (int)(id - E9);
            if (i < 512) bcat[i] = b_da[i];
            else if (i < 1024) bcat[i] = b_fb[i - 512];
            else { int r = i - 1024; bsum_p[pm(r)] = b_ih[r] + b_hh[r]; }
        } else {
            *gsync = 0;
        }
    }
}

// h0 = mean_p(enc) -> hbuf slot 0 (f16) and cbuf (f32)
__global__ __launch_bounds__(256) void k_h0(const float* __restrict__ enc,
                                            f16* __restrict__ hbuf, float* __restrict__ cbuf)
{
    int b = blockIdx.x;
    for (int h = threadIdx.x; h < CH; h += 256) {
        const float* p = enc + (size_t)b * CP * CH + h;
        float s = 0.f;
        for (int q = 0; q < CP; ++q) s += p[q * CH];
        s *= (1.f / 196.f);
        hbuf[b * CH + h] = (f16)s;
        cbuf[b * CH + h] = s;
    }
}

// ---------------------------------------------------------------------------
// K=512 GEMM, C = A[M,512] @ B[N,512]^T; f16 in, tile 128x128, BK=32,
// LDS pad (stride 40 halfwords) to avoid bank conflicts, reg-prefetch K-loop.
// ---------------------------------------------------------------------------
enum { EPI_F16B = 0, EPI_F32B = 1, EPI_PREDS = 2 };

template <int EPI>
__global__ __launch_bounds__(256) void gemm_k512(
    const f16* __restrict__ Aptr, const f16* __restrict__ Bptr, int N,
    const float* __restrict__ bias, float* __restrict__ Cf,
    f16* __restrict__ Ch, const int* __restrict__ lengths)
{
    constexpr int LD = 40;  // 32 + 8 halfword pad
    const int tid = threadIdx.x;
    const int lane = tid & 63, wave = tid >> 6;
    const int wr = wave >> 1, wc = wave & 1;
    const int bx = (EPI == EPI_PREDS) ? blockIdx.y : blockIdx.x;  // col tile
    const int by = (EPI == EPI_PREDS) ? blockIdx.x : blockIdx.y;  // row tile

    __shared__ f16 As[128 * LD];
    __shared__ f16 Bs[128 * LD];

    const f16* Ag = Aptr + (size_t)by * 128 * 512;
    const f16* Bg = Bptr + (size_t)bx * 128 * 512;

    // staging indices (fixed per thread): chunk ci covers row=ci>>2, kc=(ci&3)*8
    int srow[2], skc[2];
#pragma unroll
    for (int i = 0; i < 2; ++i) { int ci = tid + i * 256; srow[i] = ci >> 2; skc[i] = (ci & 3) * 8; }

    f32x4 acc[4][4] = {};
    f16x8 ar[2], br[2];
#pragma unroll
    for (int i = 0; i < 2; ++i) {
        ar[i] = *(const f16x8*)&Ag[(size_t)srow[i] * 512 + skc[i]];
        br[i] = *(const f16x8*)&Bg[(size_t)srow[i] * 512 + skc[i]];
    }

    const int rr = lane & 15, kg = (lane >> 4) * 8;
    for (int kt = 0; kt < 16; ++kt) {
        __syncthreads();
#pragma unroll
        for (int i = 0; i < 2; ++i) {
            *(f16x8*)&As[srow[i] * LD + skc[i]] = ar[i];
            *(f16x8*)&Bs[srow[i] * LD + skc[i]] = br[i];
        }
        __syncthreads();
        if (kt < 15) {
            int k0 = (kt + 1) * 32;
#pragma unroll
            for (int i = 0; i < 2; ++i) {
                ar[i] = *(const f16x8*)&Ag[(size_t)srow[i] * 512 + k0 + skc[i]];
                br[i] = *(const f16x8*)&Bg[(size_t)srow[i] * 512 + k0 + skc[i]];
            }
        }
        f16x8 af[4], bf[4];
#pragma unroll
        for (int mi = 0; mi < 4; ++mi) af[mi] = *(const f16x8*)&As[(wr * 64 + mi * 16 + rr) * LD + kg];
#pragma unroll
        for (int ni = 0; ni < 4; ++ni) bf[ni] = *(const f16x8*)&Bs[(wc * 64 + ni * 16 + rr) * LD + kg];
#pragma unroll
        for (int mi = 0; mi < 4; ++mi)
#pragma unroll
            for (int ni = 0; ni < 4; ++ni)
                acc[mi][ni] = __builtin_amdgcn_mfma_f32_16x16x32_f16(af[mi], bf[ni], acc[mi][ni], 0, 0, 0);
    }

    const int m0 = by * 128 + wr * 64;
    const int n0 = bx * 128 + wc * 64;
    const int r0 = (lane >> 4) * 4, cc = lane & 15;
#pragma unroll
    for (int mi = 0; mi < 4; ++mi) {
#pragma unroll
        for (int ni = 0; ni < 4; ++ni) {
#pragma unroll
            for (int r = 0; r < 4; ++r) {
                int m = m0 + mi * 16 + r0 + r;
                int n = n0 + ni * 16 + cc;
                float v = acc[mi][ni][r];
                if constexpr (EPI == EPI_F16B) {
                    Ch[(size_t)m * N + n] = (f16)(v + bias[n]);
                } else if constexpr (EPI == EPI_F32B) {
                    Cf[(size_t)m * N + n] = v + bias[n];
                } else {
                    if (n < CV) {
                        int tt = m >> 6, b = m & 63;
                        float val = ((lengths[b] - 1) > tt) ? (v + bias[n]) : 0.f;
                        __builtin_nontemporal_store(val, &Cf[(size_t)b * (CT * CV) + (size_t)tt * CV + n]);
                    }
                }
            }
        }
    }
}

// ---------------------------------------------------------------------------
// Persistent loop kernel: 64 blocks x 256 threads, 2 device barriers per step.
// Phase 1 (block b = batch): att2/gate matvec, e, softmax, awe, xh=[xawe,h].
// Phase 2 (block k): gates = xh @ Bg^T (K=1024, 32 permuted cols) + cell.
// ---------------------------------------------------------------------------
__global__ __launch_bounds__(256) void k_loop(
    const f16* __restrict__ att1, const f16* __restrict__ ench,
    const f16* __restrict__ Wdafb, const f16* __restrict__ Bg,
    const float* __restrict__ embIH, const float* __restrict__ Wfa,
    const float* __restrict__ bfa, const float* __restrict__ bcat,
    const int* __restrict__ lens, f16* __restrict__ hbuf,
    float* __restrict__ cbuf, f16* __restrict__ xh,
    float* __restrict__ alph, int* __restrict__ gsync)
{
    const int tid = threadIdx.x, lane = tid & 63, wv = tid >> 6;
    const int wr = wv >> 1, wc = wv & 1;
    const int b = blockIdx.x;  // also GEMM col-block id in phase 2

    __shared__ f16 hs[512];
    __shared__ float att2s[512], gas[512], wfas[512];
    __shared__ float es[196], als[196], red[8];
    __shared__ float awp[4][512];
    __shared__ f16 As[64 * 72];
    __shared__ f16 Bs[32 * 72];
    __shared__ float gt[64 * 33];

    for (int i = tid; i < 512; i += 256) wfas[i] = Wfa[i];
    const float bfa0 = bfa[0];
    const int len_b = lens[b];
    int nbar = 0;

    // phase-2 staging indices (fixed)
    int arow[2], akc[2];
#pragma unroll
    for (int i = 0; i < 2; ++i) { int ci = tid + i * 256; arow[i] = ci >> 3; akc[i] = (ci & 7) * 8; }
    const int brow = tid >> 3, bkc = (tid & 7) * 8;

    for (int t = 0; t < CT; ++t) {
        // ================= phase 1: attention =================
        {
            const f16x8* hp8 = (const f16x8*)(hbuf + (size_t)t * 32768 + b * 512);
            if (tid < 64) {
                f16x8 v = hp8[tid];
                ((f16x8*)hs)[tid] = v;
                ((f16x8*)(xh + b * 1024))[64 + tid] = v;  // h copy into xh[:,512:]
            }
            __syncthreads();
            // matvec: att2 (a<512) and gate arg (a>=512), a = tid + j*256
            float mv[4] = {0.f, 0.f, 0.f, 0.f};
            for (int k = 0; k < 512; k += 8) {
                f16x8 hv = ((const f16x8*)hs)[k >> 3];
#pragma unroll
                for (int j = 0; j < 4; ++j) {
                    const f16x8 wv8 = *(const f16x8*)&Wdafb[(size_t)(tid + j * 256) * 512 + k];
                    mv[j] = dot8(hv, wv8, mv[j]);
                }
            }
#pragma unroll
            for (int j = 0; j < 4; ++j) {
                int a = tid + j * 256;
                float v = mv[j] + bcat[a];
                if (a < 512) att2s[a] = v; else gas[a - 512] = v;
            }
            __syncthreads();

            // e[p] = W_fa . relu(att1[b,p,:] + att2) + bfa
            float a2r[8], wfr[8];
#pragma unroll
            for (int j = 0; j < 8; ++j) { a2r[j] = att2s[lane * 8 + j]; wfr[j] = wfas[lane * 8 + j]; }
            for (int p = wv; p < 196; p += 4) {
                f16x8 av = *(const f16x8*)&att1[((size_t)b * 196 + p) * 512 + lane * 8];
                float s = 0.f;
#pragma unroll
                for (int j = 0; j < 8; ++j) s += fmaxf((float)av[j] + a2r[j], 0.f) * wfr[j];
#pragma unroll
                for (int o = 32; o; o >>= 1) s += __shfl_down(s, o);
                if (lane == 0) es[p] = s + bfa0;
            }
            __syncthreads();

            // softmax over 196
            float ev = (tid < 196) ? es[tid] : -1e30f;
            float mx = ev;
#pragma unroll
            for (int o = 32; o; o >>= 1) mx = fmaxf(mx, __shfl_down(mx, o));
            if (lane == 0) red[wv] = mx;
            __syncthreads();
            mx = fmaxf(fmaxf(red[0], red[1]), fmaxf(red[2], red[3]));
            float ex = (tid < 196) ? __expf(ev - mx) : 0.f;
            float sm = ex;
#pragma unroll
            for (int o = 32; o; o >>= 1) sm += __shfl_down(sm, o);
            if (lane == 0) red[4 + wv] = sm;
            __syncthreads();
            sm = red[4] + red[5] + red[6] + red[7];
            float al = ex / sm;
            if (tid < 196) {
                als[tid] = al;
                alph[(size_t)b * (CT * 196) + t * 196 + tid] = ((len_b - 1) > t) ? al : 0.f;
            }
            __syncthreads();

            // awe: per wave 49 rows, lane owns h = 8*lane..8*lane+7
            float aw[8] = {};
            for (int p = wv; p < 196; p += 4) {
                float a = als[p];
                f16x8 evv = *(const f16x8*)&ench[((size_t)b * 196 + p) * 512 + lane * 8];
#pragma unroll
                for (int j = 0; j < 8; ++j) aw[j] = fmaf(a, (float)evv[j], aw[j]);
            }
#pragma unroll
            for (int j = 0; j < 8; ++j) awp[wv][lane * 8 + j] = aw[j];
            __syncthreads();
            for (int h = tid; h < 512; h += 256) {
                float s = awp[0][h] + awp[1][h] + awp[2][h] + awp[3][h];
                xh[b * 1024 + h] = (f16)(sigf(gas[h]) * s);
            }
        }
        gbar(gsync, 64 * (++nbar));

        // ============ phase 2: gates GEMM (K=1024) + LSTM cell ============
        {
            f32x4 acc[2] = {};
            f16x8 arP[2], brP;
#pragma unroll
            for (int i = 0; i < 2; ++i) arP[i] = *(const f16x8*)&xh[arow[i] * 1024 + akc[i]];
            brP = *(const f16x8*)&Bg[(size_t)(b * 32 + brow) * 1024 + bkc];

            const int rr = lane & 15, kg0 = (lane >> 4) * 8;
            for (int kt = 0; kt < 16; ++kt) {
                __syncthreads();
#pragma unroll
                for (int i = 0; i < 2; ++i) *(f16x8*)&As[arow[i] * 72 + akc[i]] = arP[i];
                *(f16x8*)&Bs[brow * 72 + bkc] = brP;
                __syncthreads();
                if (kt < 15) {
                    int k0 = (kt + 1) * 64;
#pragma unroll
                    for (int i = 0; i < 2; ++i)
                        arP[i] = *(const f16x8*)&xh[arow[i] * 1024 + k0 + akc[i]];
                    brP = *(const f16x8*)&Bg[(size_t)(b * 32 + brow) * 1024 + k0 + bkc];
                }
#pragma unroll
                for (int kk = 0; kk < 2; ++kk) {
                    int kg = kk * 32 + kg0;
                    f16x8 bfr = *(const f16x8*)&Bs[(wc * 16 + rr) * 72 + kg];
#pragma unroll
                    for (int mi = 0; mi < 2; ++mi) {
                        f16x8 afr = *(const f16x8*)&As[(wr * 32 + mi * 16 + rr) * 72 + kg];
                        acc[mi] = __builtin_amdgcn_mfma_f32_16x16x32_f16(afr, bfr, acc[mi], 0, 0, 0);
                    }
                }
            }
            // epilogue: + embIH(bias included), into LDS tile
            const int r0 = (lane >> 4) * 4, cc = lane & 15;
#pragma unroll
            for (int mi = 0; mi < 2; ++mi) {
#pragma unroll
                for (int r = 0; r < 4; ++r) {
                    int m = wr * 32 + mi * 16 + r0 + r;  // batch row
                    int j = wc * 16 + cc;                // local permuted col
                    gt[m * 33 + j] = acc[mi][r] + embIH[(size_t)(t * 64 + m) * 2048 + b * 32 + j];
                }
            }
            __syncthreads();
            // cell: block owns h-dims [8b, 8b+8) for all batches
#pragma unroll
            for (int i = 0; i < 2; ++i) {
                int e = tid + i * 256;
                int bb = e >> 3, hh = e & 7;
                float gi = gt[bb * 33 + hh];
                float gf = gt[bb * 33 + 8 + hh];
                float gg = gt[bb * 33 + 16 + hh];
                float go = gt[bb * 33 + 24 + hh];
                int ci = bb * 512 + b * 8 + hh;
                float c = sigf(gf) * cbuf[ci] + sigf(gi) * tanhf(gg);
                cbuf[ci] = c;
                hbuf[(size_t)(t + 1) * 32768 + ci] = (f16)(sigf(go) * tanhf(c));
            }
        }
        gbar(gsync, 64 * (++nbar));
    }
}

// ---------------------------------------------------------------------------
extern "C" void kernel_launch(void* const* d_in, const int* in_sizes, int n_in,
                              void* d_out, int out_size, void* d_ws, size_t ws_size,
                              hipStream_t stream)
{
    const float* enc  = (const float*)d_in[0];
    const int*   caps = (const int*)d_in[1];
    const int*   lens = (const int*)d_in[2];
    const float* emb  = (const float*)d_in[3];
    const float* W_ea = (const float*)d_in[4];
    const float* b_ea = (const float*)d_in[5];
    const float* W_da = (const float*)d_in[6];
    const float* b_da = (const float*)d_in[7];
    const float* W_fa = (const float*)d_in[8];
    const float* b_fa = (const float*)d_in[9];
    const float* W_fb = (const float*)d_in[10];
    const float* b_fb = (const float*)d_in[11];
    const float* W_ih = (const float*)d_in[12];
    const float* W_hh = (const float*)d_in[13];
    const float* b_ih = (const float*)d_in[14];
    const float* b_hh = (const float*)d_in[15];
    const float* W_fc = (const float*)d_in[16];
    const float* b_fc = (const float*)d_in[17];

    float* out = (float*)d_out;
    float* alph_out = out + (size_t)CB * CT * CV;

    char* p = (char*)d_ws;
    auto carve = [&](size_t bytes) {
        char* r = p;
        p += (bytes + 255) & ~(size_t)255;
        return r;
    };
    f16* enc_h   = (f16*)carve((size_t)12544 * 512 * 2);
    f16* att1_h  = (f16*)carve((size_t)12544 * 512 * 2);
    f16* Wea_h   = (f16*)carve((size_t)512 * 512 * 2);
    f16* Wdafb_h = (f16*)carve((size_t)1024 * 512 * 2);
    f16* WihE_p  = (f16*)carve((size_t)2048 * 512 * 2);
    f16* Bg_h    = (f16*)carve((size_t)2048 * 1024 * 2);
    f16* Wfc_h   = (f16*)carve((size_t)CVP * 512 * 2);
    f16* embg    = (f16*)carve((size_t)1280 * 512 * 2);
    float* embIH = (float*)carve((size_t)1280 * 2048 * 4);
    float* bcat  = (float*)carve(1024 * 4);
    float* bsum_p= (float*)carve(2048 * 4);
    f16* hbuf    = (f16*)carve((size_t)21 * 64 * 512 * 2);
    float* cbuf  = (float*)carve((size_t)64 * 512 * 4);
    f16* xh      = (f16*)carve((size_t)64 * 1024 * 2);
    int* gsync   = (int*)carve(256);

    hipLaunchKernelGGL(k_mega, dim3(4096), dim3(256), 0, stream,
                       enc, W_ea, W_da, W_fb, W_ih, W_hh, W_fc, emb, caps,
                       b_da, b_fb, b_ih, b_hh,
                       enc_h, Wea_h, Wdafb_h, WihE_p, Bg_h, Wfc_h, embg, bcat, bsum_p, gsync);

    hipLaunchKernelGGL(k_h0, dim3(64), dim3(256), 0, stream, enc, hbuf, cbuf);

    // att1 = enc_h @ W_ea^T + b_ea  (M=12544, N=512) -> f16
    hipLaunchKernelGGL((gemm_k512<EPI_F16B>), dim3(4, 98), dim3(256), 0, stream,
                       enc_h, Wea_h, 512, b_ea, (float*)nullptr, att1_h, (const int*)nullptr);
    // embIH = embg @ WihE_p^T + bsum_p  (M=1280, N=2048 permuted) -> f32
    hipLaunchKernelGGL((gemm_k512<EPI_F32B>), dim3(16, 10), dim3(256), 0, stream,
                       embg, WihE_p, 2048, bsum_p, embIH, (f16*)nullptr, (const int*)nullptr);

    // persistent 20-step loop
    hipLaunchKernelGGL(k_loop, dim3(64), dim3(256), 0, stream,
                       att1_h, enc_h, Wdafb_h, Bg_h, embIH, W_fa, b_fa, bcat,
                       lens, hbuf, cbuf, xh, alph_out, gsync);

    // predictions = h(1..20) @ W_fc^T + b_fc, masked scatter (grid swapped:
    // 10 consecutive blocks share one B slab -> W_fc fetched ~once)
    hipLaunchKernelGGL((gemm_k512<EPI_PREDS>), dim3(10, CVP / 128), dim3(256), 0, stream,
                       hbuf + 32768, Wfc_h, CVP, b_fc, out, (f16*)nullptr, lens);
}